// Round 6
// baseline (1299.167 us; speedup 1.0000x reference)
//
#include <hip/hip_runtime.h>
#include <cstddef>
#include <cstdint>

// Round 5: fat-tile step GEMM — BM=128 BN=256 BK=64, 4 waves (64x128 each),
// 3x48KB LDS buffers (144 KB -> 1 block/CU), depth-2 counted vmcnt(12),
// canonical chunk^(row&7) bank swizzle. Fewer, fatter iterations per CU.

namespace {

typedef short s8v __attribute__((ext_vector_type(8)));
typedef float f4v __attribute__((ext_vector_type(4)));
typedef unsigned short ushort_t;

__device__ inline unsigned short f2bf(float f) {
    union { float f; unsigned u; } v; v.f = f;
    unsigned r = v.u + 0x7fff + ((v.u >> 16) & 1);
    return (unsigned short)(r >> 16);
}
__device__ inline float bf2f(ushort_t u) {
    union { unsigned u; float f; } v; v.u = ((unsigned)u) << 16; return v.f;
}
__device__ inline float sigm_f(float x) { return 1.f / (1.f + __expf(-x)); }
__device__ inline float tanh_f(float x) {
    const float e = __expf(2.f * fabsf(x));
    return copysignf(1.f - 2.f / (e + 1.f), x);
}

#define GLOAD_LDS(gp, lp)                                              \
    __builtin_amdgcn_global_load_lds(                                  \
        (const __attribute__((address_space(1))) void*)(gp),           \
        (__attribute__((address_space(3))) void*)(lp), 16, 0, 0)

constexpr int kBufElems = 24576;  // 48 KB: A 128x64 at [0,8192), B 256x64 at [8192,24576)

// ---------------------------------------------------------------------------
// GEMM core: 128x256 tile, BK=64, 4 waves each 64x128. acc[4][8].
// A row-major bf16 [M][K]; Bt row-major bf16 [N][K].
// Swizzle: rows are 64 elems (128 B = 8 chunks of 16 B);
//   physical chunk c holds logical chunk c ^ (row & 7)  (involution).
//   Staged via pre-swizzled per-lane GLOBAL source; LDS dest linear.
// Pipeline: 3 buffers, depth 2; per iter {vmcnt(12); barrier; stage(t+2);
//   ds_read; MFMA}. Tile t's 12 loads proven landed by vmcnt before barrier.
// ---------------------------------------------------------------------------
__device__ __forceinline__ void gemm_core(
    const ushort_t* __restrict__ A1a, const ushort_t* __restrict__ A1b,
    int lda1, int K1, const ushort_t* __restrict__ B1t,
    const ushort_t* __restrict__ A2, int lda2, int K2,
    const ushort_t* __restrict__ B2t,
    int bm, int bn, ushort_t* lds, f4v acc[4][8])
{
    const int tid = threadIdx.x;
    const int wid = tid >> 6;
    const int lane = tid & 63;

    // staging geometry: lane l -> row-in-8 (l>>3), swizzled source chunk
    const int srow8 = lane >> 3;             // 0..7
    const int schunk = (lane & 7) ^ srow8;   // pre-swizzled 16B chunk

    const int n1 = K1 >> 6;
    const int n2 = (B2t != nullptr) ? (K2 >> 6) : 0;
    const int nt = n1 + n2;

    // per-lane base pointers (wave stages A rows [wid*32,+32), B rows [wid*64,+64))
    const ushort_t* Ab1 = (A1b != nullptr && bm >= 512)
                              ? A1b + (size_t)(bm - 512) * lda1
                              : A1a + (size_t)bm * lda1;
    const ushort_t* pA1 = Ab1 + (size_t)(wid * 32 + srow8) * lda1 + schunk * 8;
    const ushort_t* pB1 = B1t + (size_t)(bn + wid * 64 + srow8) * K1 + schunk * 8;
    const ushort_t* pA2 = nullptr;
    const ushort_t* pB2 = nullptr;
    if (n2 > 0) {
        pA2 = A2 + (size_t)(bm + wid * 32 + srow8) * lda2 + schunk * 8;
        pB2 = B2t + (size_t)(bn + wid * 64 + srow8) * K2 + schunk * 8;
    }

    auto stage = [&](int idx, int buf) {
        ushort_t* Lb = lds + buf * kBufElems;
        const ushort_t *pa, *pb;
        size_t la, lb;
        if (idx < n1) { pa = pA1 + (idx << 6); pb = pB1 + (idx << 6); la = lda1; lb = K1; }
        else { const int i2 = idx - n1; pa = pA2 + (i2 << 6); pb = pB2 + (i2 << 6); la = lda2; lb = K2; }
#pragma unroll
        for (int j = 0; j < 4; ++j)
            GLOAD_LDS(pa + (size_t)(j * 8) * la, Lb + (wid * 32 + j * 8) * 64);
#pragma unroll
        for (int j = 0; j < 8; ++j)
            GLOAD_LDS(pb + (size_t)(j * 8) * lb, Lb + 8192 + (wid * 64 + j * 8) * 64);
    };

    // fragment read offsets (elems), loop-invariant
    const int wr = wid >> 1, wc = wid & 1;
    const int lrow = lane & 15, lkg = lane >> 4;
    int aoff[4][2], boff[8][2];
#pragma unroll
    for (int m = 0; m < 4; ++m) {
        const int r = wr * 64 + m * 16 + lrow;
#pragma unroll
        for (int s = 0; s < 2; ++s)
            aoff[m][s] = r * 64 + (((s * 4 + lkg) ^ (r & 7)) << 3);
    }
#pragma unroll
    for (int n = 0; n < 8; ++n) {
        const int r = wc * 128 + n * 16 + lrow;
#pragma unroll
        for (int s = 0; s < 2; ++s)
            boff[n][s] = 8192 + r * 64 + (((s * 4 + lkg) ^ (r & 7)) << 3);
    }

    stage(0, 0);
    if (nt > 1) stage(1, 1);
    int sbuf = 2, cbuf = 0;
    for (int t = 0; t < nt; ++t) {
        if (t + 1 < nt) asm volatile("s_waitcnt vmcnt(12)" ::: "memory");
        else            asm volatile("s_waitcnt vmcnt(0)" ::: "memory");
        __builtin_amdgcn_s_barrier();
        __builtin_amdgcn_sched_barrier(0);
        if (t + 2 < nt) {
            stage(t + 2, sbuf);
            sbuf = (sbuf == 2) ? 0 : sbuf + 1;
        }
        const ushort_t* L = lds + cbuf * kBufElems;
#pragma unroll
        for (int s = 0; s < 2; ++s) {
            s8v a[4], b[8];
#pragma unroll
            for (int m = 0; m < 4; ++m) a[m] = *(const s8v*)(L + aoff[m][s]);
#pragma unroll
            for (int n = 0; n < 8; ++n) b[n] = *(const s8v*)(L + boff[n][s]);
            __builtin_amdgcn_s_setprio(1);
#pragma unroll
            for (int m = 0; m < 4; ++m)
#pragma unroll
                for (int n = 0; n < 8; ++n)
                    acc[m][n] = __builtin_amdgcn_mfma_f32_16x16x32_bf16(
                        a[m], b[n], acc[m][n], 0, 0, 0);
            __builtin_amdgcn_s_setprio(0);
        }
        cbuf = (cbuf == 2) ? 0 : cbuf + 1;
    }
}

// ---------------------------------------------------------------------------
// Plain GEMM: C = act(A@Bt^T + bias). M%128==0, N%256==0, K%64==0.
// ---------------------------------------------------------------------------
template <int ACT>  // 0 none, 1 tanh
__global__ __launch_bounds__(256, 1) void plain_gemm(
    const ushort_t* __restrict__ A, int lda, int K,
    const ushort_t* __restrict__ Bt,
    const float* __restrict__ bias, int bias_n,
    float* __restrict__ C, ushort_t* __restrict__ Cbf, int N)
{
    __shared__ __align__(16) ushort_t lds[3 * kBufElems];
    const int bm = blockIdx.x * 128, bn = blockIdx.y * 256;
    f4v acc[4][8] = {};
    gemm_core(A, nullptr, lda, K, Bt, nullptr, 0, 0, nullptr, bm, bn, lds, acc);

    const int tid = threadIdx.x, wid = tid >> 6, lane = tid & 63;
    const int wr = wid >> 1, wc = wid & 1, lrow = lane & 15, lkg = lane >> 4;
#pragma unroll
    for (int m = 0; m < 4; ++m) {
        const int row0 = bm + wr * 64 + m * 16 + lkg * 4;
#pragma unroll
        for (int n = 0; n < 8; ++n) {
            const int col = bn + wc * 128 + n * 16 + lrow;
            const float bv = (bias != nullptr && col < bias_n) ? bias[col] : 0.f;
#pragma unroll
            for (int r = 0; r < 4; ++r) {
                float v = acc[m][n][r] + bv;
                if (ACT == 1) v = tanh_f(v);
                const size_t o = (size_t)(row0 + r) * N + col;
                if (C != nullptr) C[o] = v;
                if (Cbf != nullptr) Cbf[o] = f2bf(v);
            }
        }
    }
}

// ---------------------------------------------------------------------------
// Fused LSTM step. Weights gate-interleaved: col' = (j>>4)*64 + g*16 + (j&15).
// ---------------------------------------------------------------------------
struct Prob {
    const ushort_t* A1a; const ushort_t* A1b; int lda1; int K1;
    const ushort_t* B1t;
    const ushort_t* A2; int lda2; int K2; const ushort_t* B2t;
    const ushort_t* Dbf;   // bf16 [M][4096] pre-gates (incl. bias), or null
    const float* bias;     // fp32 [4096] permuted combined bias, or null
    float* cst;            // fp32 [M][1024] cell state (in/out)
    ushort_t* hout;        // bf16 [M][1024] new hidden
    ushort_t* hs;          // optional extra hidden dest
    int step_s;            // -1: identity; >=0: decoder hs mapping
};

__global__ __launch_bounds__(256, 1) void lstm_step(Prob PA, int nxa, Prob PB,
                                                    int mshift)
{
    __shared__ __align__(16) ushort_t lds[3 * kBufElems];
    const int nblk = gridDim.x;
    const int wg = blockIdx.x;
    const int swz = (wg & 7) * (nblk >> 3) + (wg >> 3);
    const int nmb = 1 << mshift;
    const int nb = swz >> mshift;
    const int mb = swz & (nmb - 1);

    const bool isA = mb < nxa;
    const Prob& P = isA ? PA : PB;
    const int bm = (isA ? mb : mb - nxa) * 128;
    const int bn = nb * 256;

    f4v acc[4][8] = {};
    gemm_core(P.A1a, P.A1b, P.lda1, P.K1, P.B1t,
              P.A2, P.lda2, P.K2, P.B2t, bm, bn, lds, acc);

    const int tid = threadIdx.x, wid = tid >> 6, lane = tid & 63;
    const int wr = wid >> 1, wc = wid & 1, lrow = lane & 15, lkg = lane >> 4;

#pragma unroll
    for (int nn = 0; nn < 2; ++nn) {                  // two 64-col groups
        const int colbase = bn + wc * 128 + nn * 64;  // 64-aligned
        const int jb = (colbase >> 6) * 16 + lrow;    // hidden-unit index
#pragma unroll
        for (int m = 0; m < 4; ++m) {
            const int row0 = bm + wr * 64 + m * 16 + lkg * 4;
#pragma unroll
            for (int r = 0; r < 4; ++r) {
                const int row = row0 + r;
                float g0 = acc[m][nn * 4 + 0][r], g1 = acc[m][nn * 4 + 1][r];
                float g2 = acc[m][nn * 4 + 2][r], g3 = acc[m][nn * 4 + 3][r];
                if (P.Dbf != nullptr) {
                    const ushort_t* d = P.Dbf + (size_t)row * 4096 + colbase + lrow;
                    g0 += bf2f(d[0]); g1 += bf2f(d[16]);
                    g2 += bf2f(d[32]); g3 += bf2f(d[48]);
                }
                if (P.bias != nullptr) {
                    const float* b = P.bias + colbase + lrow;
                    g0 += b[0]; g1 += b[16]; g2 += b[32]; g3 += b[48];
                }
                const size_t ci = (size_t)row * 1024 + jb;
                const float cn = fmaf(sigm_f(g1), P.cst[ci], sigm_f(g0) * tanh_f(g2));
                const float hn = sigm_f(g3) * tanh_f(cn);
                P.cst[ci] = cn;
                const ushort_t hb = f2bf(hn);
                P.hout[ci] = hb;
                if (P.hs != nullptr) {
                    size_t d;
                    if (P.step_s >= 0) {
                        const int u = row >> 9, b = row & 511;
                        d = ((size_t)((u * 16 + P.step_s) * 512 + b) << 10) + jb;
                    } else {
                        d = ci;
                    }
                    P.hs[d] = hb;
                }
            }
        }
    }
}

// ---------------------------------------------------------------------------
// Setup kernels
// ---------------------------------------------------------------------------
template <int PERM>
__global__ __launch_bounds__(256) void transpose_to_bf16(
    const float* __restrict__ in, ushort_t* __restrict__ out,
    int K, int N, int Kp, int Np)
{
    __shared__ float tile[32][33];
    const int k0 = blockIdx.x * 32, n0 = blockIdx.y * 32;
    const int tx = threadIdx.x, ty = threadIdx.y;  // 32 x 8
#pragma unroll
    for (int q = 0; q < 4; ++q) {
        const int k = k0 + ty + 8 * q, n = n0 + tx;
        tile[ty + 8 * q][tx] = (k < K && n < N) ? in[(size_t)k * N + n] : 0.f;
    }
    __syncthreads();
#pragma unroll
    for (int q = 0; q < 4; ++q) {
        const int n = n0 + ty + 8 * q, k = k0 + tx;
        int np = n;
        if (PERM) np = ((n & 1023) >> 4) * 64 + (n >> 10) * 16 + (n & 15);
        out[(size_t)np * Kp + k] = f2bf(tile[tx][ty + 8 * q]);
    }
}

__global__ void convert_pad_bf16(const float* __restrict__ in,
                                 ushort_t* __restrict__ out,
                                 int K, int Kp, int total)
{
    const int idx = blockIdx.x * 256 + threadIdx.x;
    if (idx >= total) return;
    const int r = idx / Kp, k = idx - r * Kp;
    out[idx] = (k < K) ? f2bf(in[(size_t)r * K + k]) : (ushort_t)0;
}

__global__ void sos_init_bf16(ushort_t* __restrict__ sos)
{
    const int i = blockIdx.x * 256 + threadIdx.x;
    if (i < 512 * 320) sos[i] = ((i % 320) == 0) ? (ushort_t)0x3F80 : (ushort_t)0;
}

__global__ void permute_bias(const float* __restrict__ b1,
                             const float* __restrict__ b2,
                             float* __restrict__ out)
{
    const int c = blockIdx.x * 256 + threadIdx.x;
    if (c >= 4096) return;
    const int g = (c >> 4) & 3;
    const int j = (c >> 6) * 16 + (c & 15);
    out[c] = b1[g * 1024 + j] + b2[g * 1024 + j];
}

// One block per row of logits [16384][512] (valid cols 0..257); row = t*512+b.
__global__ __launch_bounds__(256) void logsoftmax_kernel(
    const float* __restrict__ logits, float* __restrict__ out)
{
    const int row = blockIdx.x;
    const int tid = threadIdx.x;
    const float* L = logits + (size_t)row * 512;
    const int t = row >> 9;
    const int b = row & 511;
    float* O = out + ((size_t)b * 32 + t) * 258;

    const float x0 = L[tid];
    const float x1 = (tid < 2) ? L[256 + tid] : -1e30f;

    __shared__ float sm[4];
    float m = fmaxf(x0, x1);
#pragma unroll
    for (int off = 32; off > 0; off >>= 1) m = fmaxf(m, __shfl_down(m, off));
    if ((tid & 63) == 0) sm[tid >> 6] = m;
    __syncthreads();
    m = fmaxf(fmaxf(sm[0], sm[1]), fmaxf(sm[2], sm[3]));
    __syncthreads();

    float s = expf(x0 - m) + ((tid < 2) ? expf(x1 - m) : 0.f);
#pragma unroll
    for (int off = 32; off > 0; off >>= 1) s += __shfl_down(s, off);
    if ((tid & 63) == 0) sm[tid >> 6] = s;
    __syncthreads();
    s = sm[0] + sm[1] + sm[2] + sm[3];

    const float lse = m + logf(s);
    O[tid] = x0 - lse;
    if (tid < 2) O[256 + tid] = x1 - lse;
}

}  // namespace

extern "C" void kernel_launch(void* const* d_in, const int* in_sizes, int n_in,
                              void* d_out, int out_size, void* d_ws, size_t ws_size,
                              hipStream_t stream)
{
    (void)in_sizes; (void)n_in; (void)out_size; (void)ws_size;

    const float* z    = (const float*)d_in[0];
    const float* x    = (const float*)d_in[1];
    const float* cin  = (const float*)d_in[2];
    const float* ciW  = (const float*)d_in[3];
    const float* cib  = (const float*)d_in[4];
    const float* cW1i = (const float*)d_in[5];
    const float* cW1h = (const float*)d_in[6];
    const float* cb1i = (const float*)d_in[7];
    const float* cb1h = (const float*)d_in[8];
    const float* cW2i = (const float*)d_in[9];
    const float* cW2h = (const float*)d_in[10];
    const float* cb2i = (const float*)d_in[11];
    const float* cb2h = (const float*)d_in[12];
    const float* coW  = (const float*)d_in[13];
    const float* cob  = (const float*)d_in[14];
    const float* diW  = (const float*)d_in[15];
    const float* dib  = (const float*)d_in[16];
    const float* dW1i = (const float*)d_in[17];
    const float* dW1h = (const float*)d_in[18];
    const float* db1i = (const float*)d_in[19];
    const float* db1h = (const float*)d_in[20];
    const float* dW2i = (const float*)d_in[21];
    const float* dW2h = (const float*)d_in[22];
    const float* db2i = (const float*)d_in[23];
    const float* db2h = (const float*)d_in[24];
    const float* fcW  = (const float*)d_in[25];
    const float* fcb  = (const float*)d_in[26];
    float* out = (float*)d_out;

    // ---- workspace ----
    char* wsp = (char*)d_ws;
    size_t off = 0;
    auto allocf = [&](size_t n) { float* p = (float*)(wsp + off); off += n * 4; return p; };
    auto allocb = [&](size_t n) { ushort_t* p = (ushort_t*)(wsp + off); off += n * 2; return p; };

    float* cst = allocf((size_t)3 * 1024 * 1024 + 64);
    float* c1c = cst;
    float* c2c = cst + (size_t)512 * 1024;
    float* c1d = cst + (size_t)1024 * 1024;
    float* c2d = cst + (size_t)2 * 1024 * 1024;
    float* pb1c = allocf(4096);
    float* pb2c = allocf(4096);
    float* pb1d = allocf(4096);
    float* pb2d = allocf(4096);
    float* logits = allocf((size_t)16384 * 512);

    ushort_t* h2z  = allocb((size_t)2 * (512 + 1024) * 1024);
    ushort_t* hc2A = h2z;
    ushort_t* hc2B = h2z + (size_t)512 * 1024;
    ushort_t* h2dA = h2z + (size_t)2 * 512 * 1024;
    ushort_t* h2dB = h2z + (size_t)(2 * 512 + 1024) * 1024;

    ushort_t* hc1A = allocb((size_t)512 * 1024);
    ushort_t* hc1B = allocb((size_t)512 * 1024);
    ushort_t* h1dA = allocb((size_t)1024 * 1024);
    ushort_t* h1dB = allocb((size_t)1024 * 1024);

    ushort_t* zbf    = allocb((size_t)512 * 512);
    ushort_t* cinbf  = allocb((size_t)512 * 320);
    ushort_t* sosbf  = allocb((size_t)512 * 320);
    ushort_t* xbf    = allocb((size_t)16384 * 320);
    ushort_t* chbf   = allocb((size_t)1024 * 1024);
    ushort_t* ccode  = allocb((size_t)1024 * 512);
    ushort_t* cpre   = allocb((size_t)1024 * 4096);
    ushort_t* xW1c   = allocb((size_t)512 * 4096);
    ushort_t* hsbf   = allocb((size_t)16384 * 1024);

    ushort_t* ciWt  = allocb((size_t)1024 * 512);
    ushort_t* cW1it = allocb((size_t)4096 * 320);
    ushort_t* cW1ht = allocb((size_t)4096 * 1024);
    ushort_t* cW2it = allocb((size_t)4096 * 1024);
    ushort_t* cW2ht = allocb((size_t)4096 * 1024);
    ushort_t* coWt  = allocb((size_t)512 * 1024);
    ushort_t* dtopt = allocb((size_t)4096 * 512);
    ushort_t* dbott = allocb((size_t)4096 * 320);
    ushort_t* diWt  = allocb((size_t)1024 * 512);
    ushort_t* dW1ht = allocb((size_t)4096 * 1024);
    ushort_t* dW2it = allocb((size_t)4096 * 1024);
    ushort_t* dW2ht = allocb((size_t)4096 * 1024);
    ushort_t* fcWt  = allocb((size_t)512 * 1024);

    hipMemsetAsync(cst, 0, (size_t)3 * 1024 * 1024 * 4, stream);
    hipMemsetAsync(h2z, 0, (size_t)2 * (512 + 1024) * 1024 * 2, stream);

    // ---- weight prep ----
    auto transp = [&](const float* in, ushort_t* o, int K, int N, int Kp, int Np, int perm) {
        dim3 g(Kp / 32, Np / 32), b(32, 8);
        if (perm) transpose_to_bf16<1><<<g, b, 0, stream>>>(in, o, K, N, Kp, Np);
        else      transpose_to_bf16<0><<<g, b, 0, stream>>>(in, o, K, N, Kp, Np);
    };
    transp(ciW, ciWt, 512, 1024, 512, 1024, 0);
    transp(cW1i, cW1it, 258, 4096, 320, 4096, 1);
    transp(cW1h, cW1ht, 1024, 4096, 1024, 4096, 1);
    transp(cW2i, cW2it, 1024, 4096, 1024, 4096, 1);
    transp(cW2h, cW2ht, 1024, 4096, 1024, 4096, 1);
    transp(coW, coWt, 1024, 512, 1024, 512, 0);
    transp(dW1i, dtopt, 512, 4096, 512, 4096, 1);
    transp(dW1i + (size_t)512 * 4096, dbott, 258, 4096, 320, 4096, 1);
    transp(diW, diWt, 512, 1024, 512, 1024, 0);
    transp(dW1h, dW1ht, 1024, 4096, 1024, 4096, 1);
    transp(dW2i, dW2it, 1024, 4096, 1024, 4096, 1);
    transp(dW2h, dW2ht, 1024, 4096, 1024, 4096, 1);
    transp(fcW, fcWt, 1024, 258, 1024, 512, 0);

    auto convert = [&](const float* in, ushort_t* o, int K, int Kp, int R) {
        const int total = R * Kp;
        convert_pad_bf16<<<dim3((total + 255) / 256), 256, 0, stream>>>(in, o, K, Kp, total);
    };
    convert(z, zbf, 512, 512, 512);
    convert(cin, cinbf, 258, 320, 512);
    convert(x, xbf, 258, 320, 16384);
    sos_init_bf16<<<dim3((512 * 320 + 255) / 256), 256, 0, stream>>>(sosbf);
    permute_bias<<<16, 256, 0, stream>>>(cb1i, cb1h, pb1c);
    permute_bias<<<16, 256, 0, stream>>>(cb2i, cb2h, pb2c);
    permute_bias<<<16, 256, 0, stream>>>(db1i, db1h, pb1d);
    permute_bias<<<16, 256, 0, stream>>>(db2i, db2h, pb2d);

    auto gemm = [&](int act, const ushort_t* A, int lda, int K, const ushort_t* Bt,
                    const float* bias, int bias_n,
                    float* C, ushort_t* Cbf, int M, int N) {
        dim3 g(M / 128, N / 256);
        if (act) plain_gemm<1><<<g, 256, 0, stream>>>(A, lda, K, Bt, bias, bias_n, C, Cbf, N);
        else     plain_gemm<0><<<g, 256, 0, stream>>>(A, lda, K, Bt, bias, bias_n, C, Cbf, N);
    };

    // ---- conductor init ----
    gemm(1, zbf, 512, 512, ciWt, cib, 1024, nullptr, hc1A, 512, 1024);
    gemm(0, cinbf, 320, 320, cW1it, pb1c, 4096, nullptr, xW1c, 512, 4096);

    // ---- conductor: 3 fused iterations (L1 at k=0,1; L2 at k=1,2) ----
    ushort_t* HC1[2] = {hc1A, hc1B};
    ushort_t* HC2[2] = {hc2A, hc2B};
    for (int k = 0; k <= 2; ++k) {
        Prob pa{}, pb{};
        int nxa = 0, nxb = 0;
        if (k < 2) {
            pa = {HC1[k & 1], nullptr, 1024, 1024, cW1ht,
                  nullptr, 0, 0, nullptr,
                  xW1c, nullptr, c1c, HC1[(k + 1) & 1], nullptr, -1};
            nxa = 4;
        }
        if (k >= 1) {
            pb = {HC1[k & 1], nullptr, 1024, 1024, cW2it,
                  HC2[k & 1], 1024, 1024, cW2ht,
                  nullptr, pb2c, c2c, HC2[(k + 1) & 1],
                  chbf + (size_t)(k - 1) * 512 * 1024, -1};
            nxb = 4;
        }
        const int nmb = nxa + nxb;               // 4 or 8
        const int mshift = (nmb == 4) ? 2 : 3;
        lstm_step<<<dim3(nmb * 16), 256, 0, stream>>>(pa, nxa, pb, mshift);
    }

    // ---- codes + decoder init ----
    gemm(0, chbf, 1024, 1024, coWt, cob, 512, nullptr, ccode, 1024, 512);
    gemm(0, ccode, 512, 512, dtopt, pb1d, 4096, nullptr, cpre, 1024, 4096);
    gemm(1, ccode, 512, 512, diWt, dib, 1024, nullptr, h1dA, 1024, 1024);

    // ---- decoder: 17 fused iterations (L1 at k=0..15; L2 at k=1..16) ----
    ushort_t* H1[2] = {h1dA, h1dB};
    ushort_t* H2[2] = {h2dA, h2dB};
    for (int k = 0; k <= 16; ++k) {
        Prob pa{}, pb{};
        int nxa = 0, nxb = 0;
        if (k < 16) {
            const ushort_t* plo = (k == 0) ? sosbf : (xbf + (size_t)(k - 1) * 512 * 320);
            const ushort_t* phi = xbf + (size_t)(15 + k) * 512 * 320;
            pa = {plo, phi, 320, 320, dbott,
                  H1[k & 1], 1024, 1024, dW1ht,
                  cpre, nullptr, c1d, H1[(k + 1) & 1], nullptr, -1};
            nxa = 8;
        }
        if (k >= 1) {
            pb = {H1[k & 1], nullptr, 1024, 1024, dW2it,
                  H2[k & 1], 1024, 1024, dW2ht,
                  nullptr, pb2d, c2d, H2[(k + 1) & 1], hsbf, k - 1};
            nxb = 8;
        }
        const int nmb = nxa + nxb;               // 8 or 16
        const int mshift = (nmb == 8) ? 3 : 4;
        lstm_step<<<dim3(nmb * 16), 256, 0, stream>>>(pa, nxa, pb, mshift);
    }

    // ---- projection + log_softmax ----
    gemm(0, hsbf, 1024, 1024, fcWt, fcb, 258, logits, nullptr, 16384, 512);
    logsoftmax_kernel<<<dim3(16384), 256, 0, stream>>>(logits, out);
}

// Round 7
// 1192.780 us; speedup vs baseline: 1.0892x; 1.0892x over previous
//
#include <hip/hip_runtime.h>
#include <cstddef>
#include <cstdint>

// Round 6: B-operand direct-to-register from fragment-major packed weights
// (no LDS for B; the LDS port was the measured ceiling at ~660cyc/iter).
// A (dynamic h-state) stays LDS-staged: 8KB tiles, depth-2, 3 buffers,
// 2-way-max chunk swizzle. vmcnt ledger: [A(t)2, b(t)4, A(t+1)2] -> issue
// b(t+1) -> vmcnt(6) retires exactly A(t)+b(t).

namespace {

typedef short s8v __attribute__((ext_vector_type(8)));
typedef float f4v __attribute__((ext_vector_type(4)));
typedef unsigned short ushort_t;

__device__ inline unsigned short f2bf(float f) {
    union { float f; unsigned u; } v; v.f = f;
    unsigned r = v.u + 0x7fff + ((v.u >> 16) & 1);
    return (unsigned short)(r >> 16);
}
__device__ inline float bf2f(ushort_t u) {
    union { unsigned u; float f; } v; v.u = ((unsigned)u) << 16; return v.f;
}
__device__ inline float sigm_f(float x) { return 1.f / (1.f + __expf(-x)); }
__device__ inline float tanh_f(float x) {
    const float e = __expf(2.f * fabsf(x));
    return copysignf(1.f - 2.f / (e + 1.f), x);
}

#define GLOAD_LDS(gp, lp)                                              \
    __builtin_amdgcn_global_load_lds(                                  \
        (const __attribute__((address_space(1))) void*)(gp),           \
        (__attribute__((address_space(3))) void*)(lp), 16, 0, 0)

// ---------------------------------------------------------------------------
// GEMM core: 128x128 tile, BK=32, 4 waves (2x2, wave-tile 64x64), acc[4][4].
// A row-major bf16 [M][K] staged via LDS (8KB/tile, 3 buffers, depth 2).
//   LDS chunk swizzle: phys chunk = logical chunk ^ ((row>>1)&3)  (2-way max).
// B from packed fragment-major weights: elems addr = ((nb*KB + kb)*64+lane)*8
//   -> one coalesced global_load_dwordx4 per fragment, register double-buffer.
// ---------------------------------------------------------------------------
__device__ __forceinline__ void gemm_core(
    const ushort_t* __restrict__ A1a, const ushort_t* __restrict__ A1b,
    int lda1, int K1, const ushort_t* __restrict__ W1,
    const ushort_t* __restrict__ A2, int lda2, int K2,
    const ushort_t* __restrict__ W2,
    int bm, int bn, ushort_t* lds, f4v acc[4][4])
{
    const int tid = threadIdx.x;
    const int wid = tid >> 6;
    const int lane = tid & 63;
    const int wr = wid >> 1, wc = wid & 1;
    const int lrow = lane & 15, lkg = lane >> 4;

    const int n1 = K1 >> 5;
    const int n2 = (W2 != nullptr) ? (K2 >> 5) : 0;
    const int nt = n1 + n2;

    // ---- A staging geometry: issue q covers rows (q*64 + wid*16 + lane/4) ----
    const int row0 = wid * 16 + (lane >> 2);
    const int row1 = row0 + 64;
    const int src0 = (((lane & 3) ^ ((row0 >> 1) & 3)) << 3);
    const int src1 = (((lane & 3) ^ ((row1 >> 1) & 3)) << 3);

    auto arow = [&](const ushort_t* Aa, const ushort_t* Ab, int lda,
                    int r) -> const ushort_t* {
        return (Ab != nullptr && r >= 512) ? Ab + (size_t)(r - 512) * lda
                                           : Aa + (size_t)r * lda;
    };
    const ushort_t* pA1q0 = arow(A1a, A1b, lda1, bm + row0) + src0;
    const ushort_t* pA1q1 = arow(A1a, A1b, lda1, bm + row1) + src1;
    const ushort_t* pA2q0 = nullptr;
    const ushort_t* pA2q1 = nullptr;
    if (n2 > 0) {
        pA2q0 = A2 + (size_t)(bm + row0) * lda2 + src0;
        pA2q1 = A2 + (size_t)(bm + row1) * lda2 + src1;
    }

    int sbuf = 2;
    auto stageA = [&](int idx, int buf) {
        const ushort_t *p0, *p1;
        if (idx < n1) { p0 = pA1q0 + (idx << 5); p1 = pA1q1 + (idx << 5); }
        else { const int i2 = idx - n1; p0 = pA2q0 + (i2 << 5); p1 = pA2q1 + (i2 << 5); }
        GLOAD_LDS(p0, lds + buf * 4096 + wid * 512);
        GLOAD_LDS(p1, lds + buf * 4096 + 2048 + wid * 512);
    };

    // ---- B packed bases: this wave's 4 fragments start at nb0 = bn/16 + wc*4 ----
    const int nb0 = (bn >> 4) + wc * 4;
    const ushort_t* W1l = W1 + (size_t)nb0 * n1 * 512 + lane * 8;
    const ushort_t* W2l = (n2 > 0) ? (W2 + (size_t)nb0 * n2 * 512 + lane * 8) : nullptr;

    auto loadB = [&](int t, s8v (&b)[4]) {
        const ushort_t* base; int kb, KB;
        if (t < n1) { base = W1l; kb = t; KB = n1; }
        else        { base = W2l; kb = t - n1; KB = n2; }
#pragma unroll
        for (int n = 0; n < 4; ++n)
            b[n] = *(const s8v*)(base + ((size_t)(n * KB + kb) << 9));
    };

    // ---- A fragment read offsets (swizzled), loop-invariant ----
    int aoff[4];
#pragma unroll
    for (int m = 0; m < 4; ++m) {
        const int r = wr * 64 + m * 16 + lrow;
        aoff[m] = r * 32 + ((lkg ^ ((r >> 1) & 3)) << 3);
    }

    s8v bA[4], bB[4];
    loadB(0, bA);
    stageA(0, 0);
    if (nt > 1) stageA(1, 1);

    int cbuf = 0;
    auto iter = [&](int t, s8v (&bcur)[4], s8v (&bnxt)[4]) {
        if (t + 1 < nt) loadB(t + 1, bnxt);
        if (t + 1 < nt) asm volatile("s_waitcnt vmcnt(6)" ::: "memory");
        else            asm volatile("s_waitcnt vmcnt(0)" ::: "memory");
        __builtin_amdgcn_s_barrier();
        __builtin_amdgcn_sched_barrier(0);
        if (t + 2 < nt) {
            stageA(t + 2, sbuf);
            sbuf = (sbuf == 2) ? 0 : sbuf + 1;
        }
        const ushort_t* L = lds + cbuf * 4096;
        s8v a[4];
#pragma unroll
        for (int m = 0; m < 4; ++m) a[m] = *(const s8v*)(L + aoff[m]);
        __builtin_amdgcn_s_setprio(1);
#pragma unroll
        for (int m = 0; m < 4; ++m)
#pragma unroll
            for (int n = 0; n < 4; ++n)
                acc[m][n] = __builtin_amdgcn_mfma_f32_16x16x32_bf16(
                    a[m], bcur[n], acc[m][n], 0, 0, 0);
        __builtin_amdgcn_s_setprio(0);
        cbuf = (cbuf == 2) ? 0 : cbuf + 1;
    };

    int t = 0;
    while (true) {
        iter(t, bA, bB); if (++t == nt) break;
        iter(t, bB, bA); if (++t == nt) break;
    }
}

// ---------------------------------------------------------------------------
// Plain GEMM: C = act(A@W^T + bias). M%128==0, N%128==0, K%32==0.
// ---------------------------------------------------------------------------
template <int ACT>  // 0 none, 1 tanh
__global__ __launch_bounds__(256, 2) void plain_gemm(
    const ushort_t* __restrict__ A, int lda, int K,
    const ushort_t* __restrict__ W,
    const float* __restrict__ bias, int bias_n,
    float* __restrict__ C, ushort_t* __restrict__ Cbf, int N)
{
    __shared__ __align__(16) ushort_t lds[3 * 4096];
    const int bm = blockIdx.x * 128, bn = blockIdx.y * 128;
    f4v acc[4][4] = {};
    gemm_core(A, nullptr, lda, K, W, nullptr, 0, 0, nullptr, bm, bn, lds, acc);

    const int tid = threadIdx.x, wid = tid >> 6, lane = tid & 63;
    const int wr = wid >> 1, wc = wid & 1, lrow = lane & 15, lkg = lane >> 4;
#pragma unroll
    for (int m = 0; m < 4; ++m) {
        const int row0 = bm + wr * 64 + m * 16 + lkg * 4;
#pragma unroll
        for (int n = 0; n < 4; ++n) {
            const int col = bn + wc * 64 + n * 16 + lrow;
            const float bv = (bias != nullptr && col < bias_n) ? bias[col] : 0.f;
#pragma unroll
            for (int r = 0; r < 4; ++r) {
                float v = acc[m][n][r] + bv;
                if (ACT == 1) v = tanh_f(v);
                const size_t o = (size_t)(row0 + r) * N + col;
                if (C != nullptr) C[o] = v;
                if (Cbf != nullptr) Cbf[o] = f2bf(v);
            }
        }
    }
}

// ---------------------------------------------------------------------------
// Fused LSTM step. Weights gate-interleaved: col' = (j>>4)*64 + g*16 + (j&15).
// ---------------------------------------------------------------------------
struct Prob {
    const ushort_t* A1a; const ushort_t* A1b; int lda1; int K1;
    const ushort_t* B1t;   // packed frag-major
    const ushort_t* A2; int lda2; int K2; const ushort_t* B2t;  // packed
    const ushort_t* Dbf;   // bf16 [M][4096] pre-gates (incl. bias), or null
    const float* bias;     // fp32 [4096] permuted combined bias, or null
    float* cst;            // fp32 [M][1024] cell state (in/out)
    ushort_t* hout;        // bf16 [M][1024] new hidden
    ushort_t* hs;          // optional extra hidden dest
    int step_s;            // -1: identity; >=0: decoder hs mapping
};

__global__ __launch_bounds__(256, 2) void lstm_step(Prob PA, int nxa, Prob PB,
                                                    int mshift)
{
    __shared__ __align__(16) ushort_t lds[3 * 4096];
    const int nblk = gridDim.x;
    const int wg = blockIdx.x;
    const int swz = (wg & 7) * (nblk >> 3) + (wg >> 3);
    const int nmb = 1 << mshift;
    const int nb = swz >> mshift;
    const int mb = swz & (nmb - 1);

    const bool isA = mb < nxa;
    const Prob& P = isA ? PA : PB;
    const int bm = (isA ? mb : mb - nxa) * 128;
    const int bn = nb * 128;

    f4v acc[4][4] = {};
    gemm_core(P.A1a, P.A1b, P.lda1, P.K1, P.B1t,
              P.A2, P.lda2, P.K2, P.B2t, bm, bn, lds, acc);

    const int tid = threadIdx.x, wid = tid >> 6, lane = tid & 63;
    const int wr = wid >> 1, wc = wid & 1, lrow = lane & 15, lkg = lane >> 4;
    const int colbase = bn + wc * 64;           // 64-aligned
    const int jb = (colbase >> 6) * 16 + lrow;  // hidden-unit index

#pragma unroll
    for (int m = 0; m < 4; ++m) {
        const int row0 = bm + wr * 64 + m * 16 + lkg * 4;
#pragma unroll
        for (int r = 0; r < 4; ++r) {
            const int row = row0 + r;
            float g0 = acc[m][0][r], g1 = acc[m][1][r];
            float g2 = acc[m][2][r], g3 = acc[m][3][r];
            if (P.Dbf != nullptr) {
                const ushort_t* d = P.Dbf + (size_t)row * 4096 + colbase + lrow;
                g0 += bf2f(d[0]); g1 += bf2f(d[16]);
                g2 += bf2f(d[32]); g3 += bf2f(d[48]);
            }
            if (P.bias != nullptr) {
                const float* b = P.bias + colbase + lrow;
                g0 += b[0]; g1 += b[16]; g2 += b[32]; g3 += b[48];
            }
            const size_t ci = (size_t)row * 1024 + jb;
            const float cn = fmaf(sigm_f(g1), P.cst[ci], sigm_f(g0) * tanh_f(g2));
            const float hn = sigm_f(g3) * tanh_f(cn);
            P.cst[ci] = cn;
            const ushort_t hb = f2bf(hn);
            P.hout[ci] = hb;
            if (P.hs != nullptr) {
                size_t d;
                if (P.step_s >= 0) {
                    const int u = row >> 9, b = row & 511;
                    d = ((size_t)((u * 16 + P.step_s) * 512 + b) << 10) + jb;
                } else {
                    d = ci;
                }
                P.hs[d] = hb;
            }
        }
    }
}

// ---------------------------------------------------------------------------
// Weight pack: fp32 W[K][N] -> fragment-major bf16
//   out[((nb*(Kp/32)+kb)*64 + lane)*8 + j] = bf16(W[k][n])
//   where n' = nb*16 + (lane&15), k = kb*32 + (lane>>4)*8 + j,
//   n = inv_perm(n') (PERM: gate-interleave), zero-padded to Kp x Np.
// ---------------------------------------------------------------------------
template <int PERM>
__global__ __launch_bounds__(256) void pack_frag_bf16(
    const float* __restrict__ in, ushort_t* __restrict__ out,
    int K, int N, int Kp, int Np)
{
    __shared__ float tile[32][33];
    const int kb = blockIdx.x;
    const int np0 = blockIdx.y * 32;
    const int k0 = kb * 32;
    const int tx = threadIdx.x & 31;
    const int ty = threadIdx.x >> 5;  // 0..7
#pragma unroll
    for (int q = 0; q < 4; ++q) {
        const int k = k0 + ty + 8 * q;
        const int np = np0 + tx;
        int n;
        if (PERM) n = ((np >> 4) & 3) * 1024 + (np >> 6) * 16 + (np & 15);
        else      n = np;
        tile[ty + 8 * q][tx] = (k < K && n < N) ? in[(size_t)k * N + n] : 0.f;
    }
    __syncthreads();
    const int t = threadIdx.x;
    const int rec = t >> 7;           // 0..1
    const int lane = (t >> 1) & 63;
    const int half = t & 1;
    const size_t grec = (size_t)(np0 / 16 + rec) * (Kp / 32) + kb;
    const int kl = (lane >> 4) * 8 + half * 4;
    const int nl = rec * 16 + (lane & 15);
    ushort4 v;
    v.x = f2bf(tile[kl + 0][nl]);
    v.y = f2bf(tile[kl + 1][nl]);
    v.z = f2bf(tile[kl + 2][nl]);
    v.w = f2bf(tile[kl + 3][nl]);
    *(ushort4*)(out + (grec * 64 + lane) * 8 + half * 4) = v;
}

__global__ void convert_pad_bf16(const float* __restrict__ in,
                                 ushort_t* __restrict__ out,
                                 int K, int Kp, int total)
{
    const int idx = blockIdx.x * 256 + threadIdx.x;
    if (idx >= total) return;
    const int r = idx / Kp, k = idx - r * Kp;
    out[idx] = (k < K) ? f2bf(in[(size_t)r * K + k]) : (ushort_t)0;
}

__global__ void sos_init_bf16(ushort_t* __restrict__ sos)
{
    const int i = blockIdx.x * 256 + threadIdx.x;
    if (i < 512 * 320) sos[i] = ((i % 320) == 0) ? (ushort_t)0x3F80 : (ushort_t)0;
}

__global__ void permute_bias(const float* __restrict__ b1,
                             const float* __restrict__ b2,
                             float* __restrict__ out)
{
    const int c = blockIdx.x * 256 + threadIdx.x;
    if (c >= 4096) return;
    const int g = (c >> 4) & 3;
    const int j = (c >> 6) * 16 + (c & 15);
    out[c] = b1[g * 1024 + j] + b2[g * 1024 + j];
}

// One block per row of logits [16384][384] (valid cols 0..257); row = t*512+b.
__global__ __launch_bounds__(256) void logsoftmax_kernel(
    const float* __restrict__ logits, float* __restrict__ out)
{
    const int row = blockIdx.x;
    const int tid = threadIdx.x;
    const float* L = logits + (size_t)row * 384;
    const int t = row >> 9;
    const int b = row & 511;
    float* O = out + ((size_t)b * 32 + t) * 258;

    const float x0 = L[tid];
    const float x1 = (tid < 2) ? L[256 + tid] : -1e30f;

    __shared__ float sm[4];
    float m = fmaxf(x0, x1);
#pragma unroll
    for (int off = 32; off > 0; off >>= 1) m = fmaxf(m, __shfl_down(m, off));
    if ((tid & 63) == 0) sm[tid >> 6] = m;
    __syncthreads();
    m = fmaxf(fmaxf(sm[0], sm[1]), fmaxf(sm[2], sm[3]));
    __syncthreads();

    float s = expf(x0 - m) + ((tid < 2) ? expf(x1 - m) : 0.f);
#pragma unroll
    for (int off = 32; off > 0; off >>= 1) s += __shfl_down(s, off);
    if ((tid & 63) == 0) sm[tid >> 6] = s;
    __syncthreads();
    s = sm[0] + sm[1] + sm[2] + sm[3];

    const float lse = m + logf(s);
    O[tid] = x0 - lse;
    if (tid < 2) O[256 + tid] = x1 - lse;
}

}  // namespace

extern "C" void kernel_launch(void* const* d_in, const int* in_sizes, int n_in,
                              void* d_out, int out_size, void* d_ws, size_t ws_size,
                              hipStream_t stream)
{
    (void)in_sizes; (void)n_in; (void)out_size; (void)ws_size;

    const float* z    = (const float*)d_in[0];
    const float* x    = (const float*)d_in[1];
    const float* cin  = (const float*)d_in[2];
    const float* ciW  = (const float*)d_in[3];
    const float* cib  = (const float*)d_in[4];
    const float* cW1i = (const float*)d_in[5];
    const float* cW1h = (const float*)d_in[6];
    const float* cb1i = (const float*)d_in[7];
    const float* cb1h = (const float*)d_in[8];
    const float* cW2i = (const float*)d_in[9];
    const float* cW2h = (const float*)d_in[10];
    const float* cb2i = (const float*)d_in[11];
    const float* cb2h = (const float*)d_in[12];
    const float* coW  = (const float*)d_in[13];
    const float* cob  = (const float*)d_in[14];
    const float* diW  = (const float*)d_in[15];
    const float* dib  = (const float*)d_in[16];
    const float* dW1i = (const float*)d_in[17];
    const float* dW1h = (const float*)d_in[18];
    const float* db1i = (const float*)d_in[19];
    const float* db1h = (const float*)d_in[20];
    const float* dW2i = (const float*)d_in[21];
    const float* dW2h = (const float*)d_in[22];
    const float* db2i = (const float*)d_in[23];
    const float* db2h = (const float*)d_in[24];
    const float* fcW  = (const float*)d_in[25];
    const float* fcb  = (const float*)d_in[26];
    float* out = (float*)d_out;

    // ---- workspace ----
    char* wsp = (char*)d_ws;
    size_t off = 0;
    auto allocf = [&](size_t n) { float* p = (float*)(wsp + off); off += n * 4; return p; };
    auto allocb = [&](size_t n) { ushort_t* p = (ushort_t*)(wsp + off); off += n * 2; return p; };

    float* cst = allocf((size_t)3 * 1024 * 1024 + 64);
    float* c1c = cst;
    float* c2c = cst + (size_t)512 * 1024;
    float* c1d = cst + (size_t)1024 * 1024;
    float* c2d = cst + (size_t)2 * 1024 * 1024;
    float* pb1c = allocf(4096);
    float* pb2c = allocf(4096);
    float* pb1d = allocf(4096);
    float* pb2d = allocf(4096);
    float* logits = allocf((size_t)16384 * 384);

    ushort_t* h2z  = allocb((size_t)2 * (512 + 1024) * 1024);
    ushort_t* hc2A = h2z;
    ushort_t* hc2B = h2z + (size_t)512 * 1024;
    ushort_t* h2dA = h2z + (size_t)2 * 512 * 1024;
    ushort_t* h2dB = h2z + (size_t)(2 * 512 + 1024) * 1024;

    ushort_t* hc1A = allocb((size_t)512 * 1024);
    ushort_t* hc1B = allocb((size_t)512 * 1024);
    ushort_t* h1dA = allocb((size_t)1024 * 1024);
    ushort_t* h1dB = allocb((size_t)1024 * 1024);

    ushort_t* zbf    = allocb((size_t)512 * 512);
    ushort_t* cinbf  = allocb((size_t)512 * 320);
    ushort_t* sosbf  = allocb((size_t)512 * 320);
    ushort_t* xbf    = allocb((size_t)16384 * 320);
    ushort_t* chbf   = allocb((size_t)1024 * 1024);
    ushort_t* ccode  = allocb((size_t)1024 * 512);
    ushort_t* cpre   = allocb((size_t)1024 * 4096);
    ushort_t* xW1c   = allocb((size_t)512 * 4096);
    ushort_t* hsbf   = allocb((size_t)16384 * 1024);

    // packed frag-major weights (same footprint as padded transposes)
    ushort_t* ciWp  = allocb((size_t)1024 * 512);
    ushort_t* cW1ip = allocb((size_t)4096 * 320);
    ushort_t* cW1hp = allocb((size_t)4096 * 1024);
    ushort_t* cW2ip = allocb((size_t)4096 * 1024);
    ushort_t* cW2hp = allocb((size_t)4096 * 1024);
    ushort_t* coWp  = allocb((size_t)512 * 1024);
    ushort_t* dtopp = allocb((size_t)4096 * 512);
    ushort_t* dbotp = allocb((size_t)4096 * 320);
    ushort_t* diWp  = allocb((size_t)1024 * 512);
    ushort_t* dW1hp = allocb((size_t)4096 * 1024);
    ushort_t* dW2ip = allocb((size_t)4096 * 1024);
    ushort_t* dW2hp = allocb((size_t)4096 * 1024);
    ushort_t* fcWp  = allocb((size_t)384 * 1024);

    hipMemsetAsync(cst, 0, (size_t)3 * 1024 * 1024 * 4, stream);
    hipMemsetAsync(h2z, 0, (size_t)2 * (512 + 1024) * 1024 * 2, stream);

    // ---- weight pack ----
    auto pack = [&](const float* in, ushort_t* o, int K, int N, int Kp, int Np, int perm) {
        dim3 g(Kp / 32, Np / 32);
        if (perm) pack_frag_bf16<1><<<g, 256, 0, stream>>>(in, o, K, N, Kp, Np);
        else      pack_frag_bf16<0><<<g, 256, 0, stream>>>(in, o, K, N, Kp, Np);
    };
    pack(ciW, ciWp, 512, 1024, 512, 1024, 0);
    pack(cW1i, cW1ip, 258, 4096, 320, 4096, 1);
    pack(cW1h, cW1hp, 1024, 4096, 1024, 4096, 1);
    pack(cW2i, cW2ip, 1024, 4096, 1024, 4096, 1);
    pack(cW2h, cW2hp, 1024, 4096, 1024, 4096, 1);
    pack(coW, coWp, 1024, 512, 1024, 512, 0);
    pack(dW1i, dtopp, 512, 4096, 512, 4096, 1);
    pack(dW1i + (size_t)512 * 4096, dbotp, 258, 4096, 320, 4096, 1);
    pack(diW, diWp, 512, 1024, 512, 1024, 0);
    pack(dW1h, dW1hp, 1024, 4096, 1024, 4096, 1);
    pack(dW2i, dW2ip, 1024, 4096, 1024, 4096, 1);
    pack(dW2h, dW2hp, 1024, 4096, 1024, 4096, 1);
    pack(fcW, fcWp, 1024, 258, 1024, 384, 0);

    auto convert = [&](const float* in, ushort_t* o, int K, int Kp, int R) {
        const int total = R * Kp;
        convert_pad_bf16<<<dim3((total + 255) / 256), 256, 0, stream>>>(in, o, K, Kp, total);
    };
    convert(z, zbf, 512, 512, 512);
    convert(cin, cinbf, 258, 320, 512);
    convert(x, xbf, 258, 320, 16384);
    sos_init_bf16<<<dim3((512 * 320 + 255) / 256), 256, 0, stream>>>(sosbf);
    permute_bias<<<16, 256, 0, stream>>>(cb1i, cb1h, pb1c);
    permute_bias<<<16, 256, 0, stream>>>(cb2i, cb2h, pb2c);
    permute_bias<<<16, 256, 0, stream>>>(db1i, db1h, pb1d);
    permute_bias<<<16, 256, 0, stream>>>(db2i, db2h, pb2d);

    auto gemm = [&](int act, const ushort_t* A, int lda, int K, const ushort_t* W,
                    const float* bias, int bias_n,
                    float* C, ushort_t* Cbf, int M, int N) {
        dim3 g(M / 128, N / 128);
        if (act) plain_gemm<1><<<g, 256, 0, stream>>>(A, lda, K, W, bias, bias_n, C, Cbf, N);
        else     plain_gemm<0><<<g, 256, 0, stream>>>(A, lda, K, W, bias, bias_n, C, Cbf, N);
    };

    // ---- conductor init ----
    gemm(1, zbf, 512, 512, ciWp, cib, 1024, nullptr, hc1A, 512, 1024);
    gemm(0, cinbf, 320, 320, cW1ip, pb1c, 4096, nullptr, xW1c, 512, 4096);

    // ---- conductor: 3 fused iterations (L1 at k=0,1; L2 at k=1,2) ----
    ushort_t* HC1[2] = {hc1A, hc1B};
    ushort_t* HC2[2] = {hc2A, hc2B};
    for (int k = 0; k <= 2; ++k) {
        Prob pa{}, pb{};
        int nxa = 0, nxb = 0;
        if (k < 2) {
            pa = {HC1[k & 1], nullptr, 1024, 1024, cW1hp,
                  nullptr, 0, 0, nullptr,
                  xW1c, nullptr, c1c, HC1[(k + 1) & 1], nullptr, -1};
            nxa = 4;
        }
        if (k >= 1) {
            pb = {HC1[k & 1], nullptr, 1024, 1024, cW2ip,
                  HC2[k & 1], 1024, 1024, cW2hp,
                  nullptr, pb2c, c2c, HC2[(k + 1) & 1],
                  chbf + (size_t)(k - 1) * 512 * 1024, -1};
            nxb = 4;
        }
        const int nmb = nxa + nxb;               // 4 or 8
        const int mshift = (nmb == 4) ? 2 : 3;
        lstm_step<<<dim3(nmb * 32), 256, 0, stream>>>(pa, nxa, pb, mshift);
    }

    // ---- codes + decoder init ----
    gemm(0, chbf, 1024, 1024, coWp, cob, 512, nullptr, ccode, 1024, 512);
    gemm(0, ccode, 512, 512, dtopp, pb1d, 4096, nullptr, cpre, 1024, 4096);
    gemm(1, ccode, 512, 512, diWp, dib, 1024, nullptr, h1dA, 1024, 1024);

    // ---- decoder: 17 fused iterations (L1 at k=0..15; L2 at k=1..16) ----
    ushort_t* H1[2] = {h1dA, h1dB};
    ushort_t* H2[2] = {h2dA, h2dB};
    for (int k = 0; k <= 16; ++k) {
        Prob pa{}, pb{};
        int nxa = 0, nxb = 0;
        if (k < 16) {
            const ushort_t* plo = (k == 0) ? sosbf : (xbf + (size_t)(k - 1) * 512 * 320);
            const ushort_t* phi = xbf + (size_t)(15 + k) * 512 * 320;
            pa = {plo, phi, 320, 320, dbotp,
                  H1[k & 1], 1024, 1024, dW1hp,
                  cpre, nullptr, c1d, H1[(k + 1) & 1], nullptr, -1};
            nxa = 8;
        }
        if (k >= 1) {
            pb = {H1[k & 1], nullptr, 1024, 1024, dW2ip,
                  H2[k & 1], 1024, 1024, dW2hp,
                  nullptr, pb2d, c2d, H2[(k + 1) & 1], hsbf, k - 1};
            nxb = 8;
        }
        const int nmb = nxa + nxb;               // 8 or 16
        const int mshift = (nmb == 8) ? 3 : 4;
        lstm_step<<<dim3(nmb * 32), 256, 0, stream>>>(pa, nxa, pb, mshift);
    }

    // ---- projection + log_softmax ----
    gemm(0, hsbf, 1024, 1024, fcWp, fcb, 258, logits, nullptr, 16384, 384);
    logsoftmax_kernel<<<dim3(16384), 256, 0, stream>>>(logits, out);
}